// Round 6
// baseline (546.065 us; speedup 1.0000x reference)
//
#include <hip/hip_runtime.h>
#include <math.h>

// VQ quantizer: z [N,64] fp32, codebook [512,64] fp32.
// out layout (all fp32): q_ste [N*64] | loss [1] | ids-as-float [N]
//
// R1: LDS codeword broadcast -> LDS-pipe-bound (440us, VALUBusy 39%).
// R2: uniform vector loads   -> VMEM-pipe-bound (537us, VALUBusy 24%).
// R3: s_load_dwordx16 SGPR codewords, 1 row/thread -> latency-bound (453us).
// R5: K-split x2, 8192 waves -> 327us kernel, VALUBusy 47.5%. Doubling waves
//     only gave 1.28x => NOT latency-bound: 8192 waves x 64KB = 537MB through
//     the scalar cache = 1.64 TB/s = 2.7 B/cyc/CU => SCALAR-FETCH BW WALL.
// R6: rpt=2 — each thread owns TWO z rows (128 VGPRs), so one 256B codeword
//     fetch feeds 256 cyc of FMA instead of 128. SMEM traffic halves to
//     268MB (wall ~162us); per-iter VALU now covers SMEM latency even at
//     2-3 waves/SIMD. Chains are the verified R1/R2 rpt=2 structure + the
//     verified R5 s_load asm; merge tie-break unchanged (absmax 0.0 so far).

constexpr int D   = 64;
constexpr int D4  = 16;     // float4s per row
constexpr int K   = 512;
constexpr int KHALF = 256;
constexpr int BLOCK  = 256;
constexpr int ROWSLOTS = 128;           // threads per k-half
constexpr int ROWS_PER_BLOCK = 256;     // 2 rows/thread x 128 slots

typedef float v16f __attribute__((ext_vector_type(16)));

#define FMA4(acc, zz, cc) do { \
  acc = fmaf((zz).x, (cc).x, acc); \
  acc = fmaf((zz).y, (cc).y, acc); \
  acc = fmaf((zz).z, (cc).z, acc); \
  acc = fmaf((zz).w, (cc).w, acc); } while (0)

#define CHUNK_FMA(acc, zreg, vec, off) do { \
  acc = fmaf((zreg).x, (vec)[(off)+0], acc); \
  acc = fmaf((zreg).y, (vec)[(off)+1], acc); \
  acc = fmaf((zreg).z, (vec)[(off)+2], acc); \
  acc = fmaf((zreg).w, (vec)[(off)+3], acc); } while (0)

__global__ __launch_bounds__(BLOCK)
void vq_main(const float* __restrict__ z, const float* __restrict__ cbk,
             float* __restrict__ out, float* __restrict__ lossAcc, int N)
{
    __shared__ float c2s[K];                 // 2 KB
    __shared__ float mb0f[ROWSLOTS];         // high-half merge: row0 best
    __shared__ int   mb0i[ROWSLOTS];
    __shared__ float mb1f[ROWSLOTS];         // high-half merge: row1 best
    __shared__ int   mb1i[ROWSLOTS];
    __shared__ float wsum[BLOCK / 64];

    const int tid   = threadIdx.x;
    const int local = tid & (ROWSLOTS - 1); // row slot (waves 0&2 share rows)
    const int khalf = tid >> 7;             // wave-uniform k-half selector
    const long base = (long)blockIdx.x * ROWS_PER_BLOCK;
    const long r0   = base + local;
    const long r1   = base + ROWSLOTS + local;

    // Codeword squared norms — identical chain to R1-R5.
    for (int k = tid; k < K; k += BLOCK) {
        const float4* c4 = (const float4*)(cbk + (long)k * D);
        float s = 0.f;
        #pragma unroll
        for (int i = 0; i < D4; ++i) { float4 c = c4[i]; FMA4(s, c, c); }
        c2s[k] = s;
    }

    // Two z rows into registers (128 VGPRs) + row norms — identical chains.
    float4 z0[D4], z1[D4];
    {
        const float4* zp0 = (const float4*)(z + r0 * D);
        const float4* zp1 = (const float4*)(z + r1 * D);
        #pragma unroll
        for (int i = 0; i < D4; ++i) { z0[i] = zp0[i]; z1[i] = zp1[i]; }
    }
    float z2_0 = 0.f, z2_1 = 0.f;
    #pragma unroll
    for (int i = 0; i < D4; ++i) { FMA4(z2_0, z0[i], z0[i]); }
    #pragma unroll
    for (int i = 0; i < D4; ++i) { FMA4(z2_1, z1[i], z1[i]); }

    __syncthreads(); // c2s ready

    float best0 = INFINITY, best1 = INFINITY;
    int   bi0 = 0, bi1 = 0;

    // readfirstlane: compiler-known-uniform so cp stays an SGPR pair.
    const int kbeg_s = __builtin_amdgcn_readfirstlane(khalf * KHALF);
    const int kbeg   = khalf * KHALF;
    const float* cp  = cbk + (long)kbeg_s * D;

    #pragma unroll 1
    for (int kk = 0; kk < KHALF; ++kk) {
        const int k = kbeg + kk;
        // Whole codeword -> 64 SGPRs, once per wave (SMEM pipe).
        v16f ca, cb, cc, cd;
        asm volatile("s_load_dwordx16 %0, %1, 0x0"  : "=&s"(ca) : "s"(cp));
        asm volatile("s_load_dwordx16 %0, %1, 0x40" : "=&s"(cb) : "s"(cp));
        asm volatile("s_load_dwordx16 %0, %1, 0x80" : "=&s"(cc) : "s"(cp));
        asm volatile("s_load_dwordx16 %0, %1, 0xc0" : "=&s"(cd) : "s"(cp));
        asm volatile("s_waitcnt lgkmcnt(0)"
                     : "+s"(ca), "+s"(cb), "+s"(cc), "+s"(cd));

        // Four independent chains (2 per row) — identical mapping to R1/R2:
        // even chunks -> a*, odd chunks -> b*.
        float a0 = 0.f, b0 = 0.f, a1 = 0.f, b1 = 0.f;
        CHUNK_FMA(a0, z0[0],  ca, 0);  CHUNK_FMA(b0, z0[1],  ca, 4);
        CHUNK_FMA(a1, z1[0],  ca, 0);  CHUNK_FMA(b1, z1[1],  ca, 4);
        CHUNK_FMA(a0, z0[2],  ca, 8);  CHUNK_FMA(b0, z0[3],  ca, 12);
        CHUNK_FMA(a1, z1[2],  ca, 8);  CHUNK_FMA(b1, z1[3],  ca, 12);
        CHUNK_FMA(a0, z0[4],  cb, 0);  CHUNK_FMA(b0, z0[5],  cb, 4);
        CHUNK_FMA(a1, z1[4],  cb, 0);  CHUNK_FMA(b1, z1[5],  cb, 4);
        CHUNK_FMA(a0, z0[6],  cb, 8);  CHUNK_FMA(b0, z0[7],  cb, 12);
        CHUNK_FMA(a1, z1[6],  cb, 8);  CHUNK_FMA(b1, z1[7],  cb, 12);
        CHUNK_FMA(a0, z0[8],  cc, 0);  CHUNK_FMA(b0, z0[9],  cc, 4);
        CHUNK_FMA(a1, z1[8],  cc, 0);  CHUNK_FMA(b1, z1[9],  cc, 4);
        CHUNK_FMA(a0, z0[10], cc, 8);  CHUNK_FMA(b0, z0[11], cc, 12);
        CHUNK_FMA(a1, z1[10], cc, 8);  CHUNK_FMA(b1, z1[11], cc, 12);
        CHUNK_FMA(a0, z0[12], cd, 0);  CHUNK_FMA(b0, z0[13], cd, 4);
        CHUNK_FMA(a1, z1[12], cd, 0);  CHUNK_FMA(b1, z1[13], cd, 4);
        CHUNK_FMA(a0, z0[14], cd, 8);  CHUNK_FMA(b0, z0[15], cd, 12);
        CHUNK_FMA(a1, z1[14], cd, 8);  CHUNK_FMA(b1, z1[15], cd, 12);

        float dot0 = a0 + b0;
        float dot1 = a1 + b1;
        float c2 = c2s[k];
        float d0 = fmaf(-2.f, dot0, z2_0) + c2;
        float d1 = fmaf(-2.f, dot1, z2_1) + c2;
        if (d0 < best0) { best0 = d0; bi0 = k; }
        if (d1 < best1) { best1 = d1; bi1 = k; }
        cp += D;
    }

    // Publish high half, merge in low half. Tie (==) keeps half 0 = lower k,
    // matching numpy argmin first-min semantics.
    if (khalf == 1) {
        mb0f[local] = best0; mb0i[local] = bi0;
        mb1f[local] = best1; mb1i[local] = bi1;
    }
    __syncthreads();

    float lacc = 0.f;
    if (khalf == 0) {
        float dhi0 = mb0f[local]; int ihi0 = mb0i[local];
        float dhi1 = mb1f[local]; int ihi1 = mb1i[local];
        if (dhi0 < best0) { best0 = dhi0; bi0 = ihi0; }
        if (dhi1 < best1) { best1 = dhi1; bi1 = ihi1; }

        // Epilogue — identical ops to R1-R5.
        {
            const float4* qp = (const float4*)(cbk + (long)bi0 * D);
            float4* o = (float4*)(out + r0 * D);
            #pragma unroll
            for (int i = 0; i < D4; ++i) {
                float4 q = qp[i], zz = z0[i], u, qs;
                u.x = q.x - zz.x; u.y = q.y - zz.y; u.z = q.z - zz.z; u.w = q.w - zz.w;
                qs.x = zz.x + u.x; qs.y = zz.y + u.y; qs.z = zz.z + u.z; qs.w = zz.w + u.w;
                FMA4(lacc, u, u);
                o[i] = qs;
            }
        }
        {
            const float4* qp = (const float4*)(cbk + (long)bi1 * D);
            float4* o = (float4*)(out + r1 * D);
            #pragma unroll
            for (int i = 0; i < D4; ++i) {
                float4 q = qp[i], zz = z1[i], u, qs;
                u.x = q.x - zz.x; u.y = q.y - zz.y; u.z = q.z - zz.z; u.w = q.w - zz.w;
                qs.x = zz.x + u.x; qs.y = zz.y + u.y; qs.z = zz.z + u.z; qs.w = zz.w + u.w;
                FMA4(lacc, u, u);
                o[i] = qs;
            }
        }

        float* idsOut = out + (long)N * D + 1;
        idsOut[r0] = (float)bi0;
        idsOut[r1] = (float)bi1;
    }

    // Loss: wave shuffle reduce -> per-wave LDS -> one atomicAdd per block.
    // (waves 2-3 contribute 0.)
    #pragma unroll
    for (int off = 32; off > 0; off >>= 1) lacc += __shfl_down(lacc, off, 64);
    if ((tid & 63) == 0) wsum[tid >> 6] = lacc;
    __syncthreads();
    if (tid == 0) {
        float s = wsum[0] + wsum[1] + wsum[2] + wsum[3];
        atomicAdd(lossAcc, s);
    }
}

__global__ void vq_finalize(float* __restrict__ out,
                            const float* __restrict__ lossAcc, int N)
{
    out[(long)N * D] = 1.25f * (lossAcc[0] / (float)((long)N * D));
}

extern "C" void kernel_launch(void* const* d_in, const int* in_sizes, int n_in,
                              void* d_out, int out_size, void* d_ws, size_t ws_size,
                              hipStream_t stream)
{
    const float* z   = (const float*)d_in[0];
    const float* cbk = (const float*)d_in[1];
    float* out = (float*)d_out;
    float* ws  = (float*)d_ws;
    const int N = in_sizes[0] / D;

    hipMemsetAsync(ws, 0, sizeof(float), stream);
    const int blocks = N / ROWS_PER_BLOCK;
    vq_main<<<blocks, BLOCK, 0, stream>>>(z, cbk, out, ws, N);
    vq_finalize<<<1, 1, 0, stream>>>(out, ws, N);
}